// Round 5
// baseline (1061.651 us; speedup 1.0000x reference)
//
#include <hip/hip_runtime.h>

// ---------------- problem constants ----------------
#define E_EDGES 64800
#define NC      842
#define NB      8          // b*t = 2*4
#define FIN     78
#define E_LAT   5894
#define NROWS_NODE (NB*NC)   // 6736
#define EPB      8           // edges per tile (x 8 batches = 64 rows, MF=4)
#define NT_EDGE  8100        // 64800/8 exact
#define EDGE_GRID 256        // persistent blocks (1/CU), weights in registers
#define NODE_B   421
#define TAIL_B   192         // tail blocks fused into node dispatch

// output layout (flat float32)
#define OUT_IDX_OFF   1724416
#define OUT_IDX_N     11788
#define OUT_ATTR_OFF  1736204

// workspace layout (bytes)
#define AGG_OFF    0
#define CNT_OFF    6897664
#define CUR_OFF    6901032
#define SSRC_OFF   6904400
#define SDST_OFF   7163600
#define SATTR_OFF  7293200
#define WPACK_OFF  7811600

// packed-weight element offsets (bf16 elements)
#define WOFF_E0 0
#define WOFF_E1 40960
#define WOFF_E2 106496
#define WOFF_N0 172032
#define WOFF_N1 262144
#define WOFF_N2 327680
#define WOFF_R0 393216
#define WOFF_R1 401408
#define WOFF_R2 466944

// LDS strides (bf16 elems): dword stride ≡ 3 or 5 (mod 8) keeps b128 A-frag
// reads ≤2-way bank-aliased (free).  262 -> 131 dw (3 mod 8); 362 -> 181 dw (5 mod 8).
#define SH   262
#define SA_N 362

typedef __bf16 bf16x8 __attribute__((ext_vector_type(8)));
typedef float  f32x4  __attribute__((ext_vector_type(4)));

__device__ __forceinline__ unsigned short f2bf(float f) {   // RNE (pack_weights only)
    unsigned u = __builtin_bit_cast(unsigned, f);
    return (unsigned short)((u + 0x7fffu + ((u >> 16) & 1u)) >> 16);
}
// RTZ pack of two floats into two bf16 in one v_perm_b32
__device__ __forceinline__ unsigned packRTZ(float lo, float hi) {
    return __builtin_amdgcn_perm(__builtin_bit_cast(unsigned, hi),
                                 __builtin_bit_cast(unsigned, lo), 0x07060302u);
}

template<int MF, int NF>
__device__ __forceinline__ void zero_acc(f32x4 (&acc)[MF][NF]) {
#pragma unroll
    for (int mf = 0; mf < MF; ++mf)
#pragma unroll
        for (int nf = 0; nf < NF; ++nf)
            acc[mf][nf] = (f32x4){0.f, 0.f, 0.f, 0.f};
}

// ---- K-loop with B entirely in registers (edge kernel, 8 waves x 32 cols) ----
// No global traffic, no vmcnt in the loop; only A ds_reads + MFMA.
// All wr indices are compile-time after unroll (rule: no runtime reg indexing).
template<int MF, int NKS>
__device__ __forceinline__ void run_layer_reg(const unsigned short* lA, int strideA,
                                              const bf16x8 (&wr)[NKS][2],
                                              int m15, int q, f32x4 (&acc)[MF][2]) {
#pragma unroll
    for (int kk = 0; kk < NKS; ++kk) {
        bf16x8 a[MF];
#pragma unroll
        for (int mf = 0; mf < MF; ++mf)
            a[mf] = *(const bf16x8*)(lA + (mf * 16 + m15) * strideA + kk * 32 + q * 8);
#pragma unroll
        for (int nf = 0; nf < 2; ++nf)
#pragma unroll
            for (int mf = 0; mf < MF; ++mf)
                acc[mf][nf] = __builtin_amdgcn_mfma_f32_16x16x32_bf16(a[mf], wr[kk][nf], acc[mf][nf], 0, 0, 0);
    }
}

// C[MF*16 rows x 64-col wave slice] += A_lds * Wpacked, B-fragment prefetch (node/tail).
template<int MF, int NKS>
__device__ __forceinline__ void run_layer(const unsigned short* lA, int strideA,
                                          const unsigned short* Wp, int nfg0,
                                          int m15, int q, f32x4 (&acc)[MF][4]) {
    const unsigned short* wp0 = Wp + (size_t)nfg0 * 512 + (threadIdx.x & 63) * 8;
    bf16x8 bcur[4], bnxt[4];
#pragma unroll
    for (int nf = 0; nf < 4; ++nf) bcur[nf] = *(const bf16x8*)(wp0 + nf * 512);
#pragma unroll
    for (int kk = 0; kk < NKS; ++kk) {
        if (kk + 1 < NKS) {
#pragma unroll
            for (int nf = 0; nf < 4; ++nf)
                bnxt[nf] = *(const bf16x8*)(wp0 + (size_t)(kk + 1) * 16 * 512 + nf * 512);
        }
        bf16x8 a[MF];
#pragma unroll
        for (int mf = 0; mf < MF; ++mf)
            a[mf] = *(const bf16x8*)(lA + (mf * 16 + m15) * strideA + kk * 32 + q * 8);
#pragma unroll
        for (int nf = 0; nf < 4; ++nf)
#pragma unroll
            for (int mf = 0; mf < MF; ++mf)
                acc[mf][nf] = __builtin_amdgcn_mfma_f32_16x16x32_bf16(a[mf], bcur[nf], acc[mf][nf], 0, 0, 0);
#pragma unroll
        for (int nf = 0; nf < 4; ++nf) bcur[nf] = bnxt[nf];
    }
}

// S[row*stride+col] = bf16_rtz(leaky(acc + bias[col])); leaky = max(y, 0.01y)
template<int MF, int NF>
__device__ __forceinline__ void epi_act(unsigned short* Sb, int stride, const f32x4 (&acc)[MF][NF],
                                        const float* bias, int colbase, int m15, int q) {
#pragma unroll
    for (int nf = 0; nf < NF; ++nf) {
        int col = colbase + nf * 16 + m15;
        float bv = bias[col];
#pragma unroll
        for (int mf = 0; mf < MF; ++mf)
#pragma unroll
            for (int r4 = 0; r4 < 4; ++r4) {
                int row = mf * 16 + q * 4 + r4;
                float y = acc[mf][nf][r4] + bv;
                y = fmaxf(y, 0.01f * y);
                Sb[row * stride + col] = (unsigned short)(__builtin_bit_cast(unsigned, y) >> 16);
            }
    }
}

// ---------------- weight packing ----------------
__global__ void pack_weights(const float* s0, const float* s1, const float* s2,
                             const float* s3, const float* s4, const float* s5,
                             const float* s6, const float* s7, const float* s8,
                             unsigned short* wp) {
    const int ksA[9]  = {5, 8, 8, 11, 8, 8, 1, 8, 8};
    const int kaA[9]  = {158, 256, 256, 334, 256, 256, 2, 256, 256};
    const int offA[9] = {WOFF_E0, WOFF_E1, WOFF_E2, WOFF_N0, WOFF_N1, WOFF_N2,
                         WOFF_R0, WOFF_R1, WOFF_R2};
    const float* srcs[9] = {s0, s1, s2, s3, s4, s5, s6, s7, s8};
    int rem = blockIdx.x;
    int l = 0;
    while (rem >= ksA[l] * 16) { rem -= ksA[l] * 16; ++l; }
    int kk = rem >> 4, nf = rem & 15;
    int lane = threadIdx.x >> 3, j = threadIdx.x & 7;
    int k = kk * 32 + (lane >> 4) * 8 + j;
    int n = nf * 16 + (lane & 15);
    float v = (k < kaA[l]) ? srcs[l][k * 256 + n] : 0.f;
    wp[(size_t)offA[l] + (size_t)(kk * 16 + nf) * 512 + lane * 8 + j] = f2bf(v);
}

// ---------------- counting sort of edges by dst (+ gather sorted meta) ----------------
__global__ void hist_kernel(const int* __restrict__ dstA, int* __restrict__ cnt) {
    int e = blockIdx.x * 256 + threadIdx.x;
    if (e < E_EDGES) atomicAdd(&cnt[dstA[e]], 1);
}
__global__ void scan_kernel(const int* __restrict__ cnt, int* __restrict__ cursor) {
    __shared__ int s[1024];
    int t = threadIdx.x;
    s[t] = (t < NC) ? cnt[t] : 0;
    __syncthreads();
    for (int d = 1; d < 1024; d <<= 1) {
        int v = (t >= d) ? s[t - d] : 0;
        __syncthreads();
        s[t] += v;
        __syncthreads();
    }
    if (t < NC) cursor[t] = (t == 0) ? 0 : s[t - 1];
}
__global__ void scatter_kernel(const int* __restrict__ srcA, const int* __restrict__ dstA,
                               const float* __restrict__ eattr, int* __restrict__ cursor,
                               int* __restrict__ ssrc, short* __restrict__ sdst,
                               float2* __restrict__ sattr) {
    int e = blockIdx.x * 256 + threadIdx.x;
    if (e < E_EDGES) {
        int d = dstA[e];
        int p = atomicAdd(&cursor[d], 1);
        ssrc[p] = srcA[e];
        sdst[p] = (short)d;
        sattr[p] = ((const float2*)eattr)[e];
    }
}

// ------- persistent edge MLP: 512 thr (8 waves x 32 cols), weights in regs ----
// Each block preloads its 32-col slice of all 3 layers (168 VGPR/lane) ONCE,
// then grid-strides over 8100 tiles of 64 rows (8 edges x 8 batches).
// The K-loop has zero global traffic: it kills the weight L2-stream (~11K
// cyc/32-rows), all B-load latency, and the B-prefetch VALU addressing.
__global__ __launch_bounds__(512, 2) void edge_mlp_kernel(
    const float* __restrict__ x, const float* __restrict__ h3,
    const float* __restrict__ eb0, const float* __restrict__ eb1, const float* __restrict__ eb2,
    const unsigned short* __restrict__ wpack, const int* __restrict__ ssrc,
    const short* __restrict__ sdst, const float2* __restrict__ sattr,
    float* __restrict__ agg) {
    __shared__ __align__(16) unsigned short S[64 * SH];   // overlay: A(160) then H(256)
    __shared__ short dstl[EPB];
    __shared__ unsigned char starts[EPB + 4];
    __shared__ int nseg;

    const int tid = threadIdx.x, lane = tid & 63, w = tid >> 6;   // w in 0..7
    const int m15 = lane & 15, q = lane >> 4;

    // ---- preload this wave's 32-col weight slice into registers ----
    const unsigned short* wb = wpack + (size_t)(w * 2) * 512 + lane * 8;
    bf16x8 wE0[5][2], wE1[8][2], wE2[8][2];
#pragma unroll
    for (int kk = 0; kk < 5; ++kk)
#pragma unroll
        for (int nf = 0; nf < 2; ++nf)
            wE0[kk][nf] = *(const bf16x8*)(wb + WOFF_E0 + (kk * 16 + nf) * 512);
#pragma unroll
    for (int kk = 0; kk < 8; ++kk)
#pragma unroll
        for (int nf = 0; nf < 2; ++nf) {
            wE1[kk][nf] = *(const bf16x8*)(wb + WOFF_E1 + (kk * 16 + nf) * 512);
            wE2[kk][nf] = *(const bf16x8*)(wb + WOFF_E2 + (kk * 16 + nf) * 512);
        }
    float bnf[2];
#pragma unroll
    for (int nf = 0; nf < 2; ++nf) bnf[nf] = eb2[w * 32 + nf * 16 + m15];

    // staging roles: 8 threads per row, 64 rows (row = b*8 + e)
    const int rr = tid >> 3, j = tid & 7;
    const int sb = rr >> 3, se = rr & 7;
    const int ebase = (q & 1) * 4;   // flush: lane's edge range
    const int bh = q >> 1;           // flush: lane's batch half

    for (int t = blockIdx.x; t < NT_EDGE; t += gridDim.x) {
        const int base = t * EPB;
        __syncthreads();   // prev iter: flush reads dstl/starts; L2 reads S

        if (tid < EPB) dstl[tid] = sdst[base + tid];
        if (tid == 0) {    // serial segment scan (8 edges)
            int ns = 0; short prev = -2;
            for (int r = 0; r < EPB; ++r) {
                short d = sdst[base + r];
                if (d != prev) { starts[ns++] = (unsigned char)r; prev = d; }
            }
            starts[ns] = EPB;
            nseg = ns;
        }

        // stage layer-0 input [x(78)|h3(78)|attr(2)|pad(2)] at stride SH, RTZ pack
        {
            const int eg = base + se;
            const float* xr = x + ((size_t)sb * E_EDGES + ssrc[eg]) * FIN;
            const float* hr = h3 + (int)sdst[eg] * FIN;
            unsigned short* Sr = S + rr * SH;
#pragma unroll
            for (int tt = 0; tt < 5; ++tt) {
                int p = j + 8 * tt;
                if (p < 39) {
                    float2 f = *(const float2*)(xr + 2 * p);
                    float2 g = *(const float2*)(hr + 2 * p);
                    *(unsigned*)(Sr + 2 * p) = packRTZ(f.x, f.y);
                    *(unsigned*)(Sr + 78 + 2 * p) = packRTZ(g.x, g.y);
                } else if (p == 39) {
                    float2 a2 = sattr[eg];
                    *(unsigned*)(Sr + 156) = packRTZ(a2.x, a2.y);
                    *(unsigned*)(Sr + 158) = 0;
                }
            }
        }
        __syncthreads();

        f32x4 acc[4][2];
        zero_acc(acc);
        run_layer_reg<4, 5>(S, SH, wE0, m15, q, acc);   // K=160
        __syncthreads();
        epi_act(S, SH, acc, eb0, w * 32, m15, q);
        __syncthreads();

        zero_acc(acc);
        run_layer_reg<4, 8>(S, SH, wE1, m15, q, acc);   // K=256
        __syncthreads();
        epi_act(S, SH, acc, eb1, w * 32, m15, q);
        __syncthreads();

        zero_acc(acc);
        run_layer_reg<4, 8>(S, SH, wE2, m15, q, acc);   // K=256

        // segment reduce + atomic flush.
        // Lane holds rows (mf*16+q*4+r4) = batch b=2mf+bh, edge e=ebase+r4.
        // shfl_xor(16) combines the two edge halves (q^1: same b, other e-range).
        const int ns = nseg;
#pragma unroll
        for (int nf = 0; nf < 2; ++nf) {
            const float bv = bnf[nf];
            for (int s = 0; s < ns; ++s) {
                const int lo = starts[s], hi = starts[s + 1];
                const int dc = dstl[lo];
#pragma unroll
                for (int mf = 0; mf < 4; ++mf) {
                    float tv = 0.f;
#pragma unroll
                    for (int r4 = 0; r4 < 4; ++r4) {
                        int e = ebase + r4;
                        tv += (e >= lo && e < hi) ? acc[mf][nf][r4] : 0.f;
                    }
                    tv += __shfl_xor(tv, 16, 64);
                    if ((q & 1) == 0) {
                        atomicAdd(&agg[((size_t)(2 * mf + bh) * NC + dc) * 256
                                       + w * 32 + nf * 16 + m15],
                                  tv + bv * (float)(hi - lo));
                    }
                }
            }
        }
    }
}

// ------- node MLP (16-row tiles, MF=1, overlay) + fused tail blocks ----------
__global__ __launch_bounds__(256, 4) void node_tail_kernel(
    const float* __restrict__ h3, const float* __restrict__ agg,
    const float* __restrict__ nb0, const float* __restrict__ nb1, const float* __restrict__ nb2,
    const unsigned short* __restrict__ wpack, float* __restrict__ out,
    const float* __restrict__ la, const float* __restrict__ rb0,
    const float* __restrict__ rb1, const float* __restrict__ rb2,
    const float* __restrict__ rWs, const float* __restrict__ rbs,
    const int* __restrict__ lei) {
    __shared__ __align__(16) unsigned short S[32 * SH];   // covers 16*SA_N too

    const int tid = threadIdx.x, lane = tid & 63, w = tid >> 6;
    const int m15 = lane & 15, q = lane >> 4;

    if (blockIdx.x >= NODE_B) {   // ---------------- tail path ----------------
        const int blk = blockIdx.x - NODE_B;
        if (blk >= 185) {   // idx passthrough: float(latent_edge_index)
            for (int i = (blk - 185) * 256 + tid; i < OUT_IDX_N; i += 7 * 256)
                out[OUT_IDX_OFF + i] = (float)lei[i];
            return;
        }
        const int base = blk * 32;
        {   // stage [la(2)|zero(30)] at stride SH; 8 lanes per row, 16 pairs
            const int rr = tid >> 3, jj = tid & 7;
            unsigned short* Sr = S + rr * SH;
            unsigned v0 = 0;
            if (jj == 0 && base + rr < E_LAT) {
                float2 f = *(const float2*)(la + (size_t)(base + rr) * 2);
                v0 = packRTZ(f.x, f.y);
            }
            *(unsigned*)(Sr + 2 * jj) = v0;
            *(unsigned*)(Sr + 2 * (jj + 8)) = 0;
        }
        __syncthreads();

        f32x4 acc[2][4];
        zero_acc(acc);
        run_layer<2, 1>(S, SH, wpack + WOFF_R0, w * 4, m15, q, acc);   // K=32 (2 real)
        __syncthreads();
        epi_act(S, SH, acc, rb0, w * 64, m15, q);
        __syncthreads();

        zero_acc(acc);
        run_layer<2, 8>(S, SH, wpack + WOFF_R1, w * 4, m15, q, acc);
        __syncthreads();
        epi_act(S, SH, acc, rb1, w * 64, m15, q);
        __syncthreads();

        zero_acc(acc);
        run_layer<2, 8>(S, SH, wpack + WOFF_R2, w * 4, m15, q, acc);

        float* outA = out + OUT_ATTR_OFF;
#pragma unroll
        for (int nf = 0; nf < 4; ++nf) {
            int col = w * 64 + nf * 16 + m15;
            float bv = rb2[col] + rbs[col];
            float ws0 = rWs[col], ws1 = rWs[256 + col];
#pragma unroll
            for (int mf = 0; mf < 2; ++mf)
#pragma unroll
                for (int r4 = 0; r4 < 4; ++r4) {
                    int row = mf * 16 + q * 4 + r4;
                    int e = base + row;
                    if (e < E_LAT) {
                        float v = acc[mf][nf][r4] + bv + la[e * 2] * ws0 + la[e * 2 + 1] * ws1;
                        outA[(size_t)e * 256 + col] = v;
                    }
                }
        }
        return;
    }

    // ---------------- node path ----------------
    const int base = blockIdx.x * 16;

    // stage [h3(78)|agg(256)|zero(18)] at stride SA_N; 16 lanes per row
    {
        const int rr = tid >> 4, l16 = tid & 15;
        const int jj = base + rr;
        const int vl = jj < NROWS_NODE;
        const int c = vl ? jj % NC : 0;
        const float* hr = h3 + c * FIN;
        const float* ar = agg + (size_t)jj * 256;
        unsigned short* Sr = S + rr * SA_N;
#pragma unroll
        for (int tt = 0; tt < 12; ++tt) {
            int p = l16 + 16 * tt;
            if (p < 39) {
                float2 f = *(const float2*)(hr + 2 * p);
                *(unsigned*)(Sr + 2 * p) = packRTZ(f.x, f.y);
            } else if (p < 167) {
                unsigned v = 0;
                if (vl) { float2 f = *(const float2*)(ar + 2 * p - 78); v = packRTZ(f.x, f.y); }
                *(unsigned*)(Sr + 2 * p) = v;
            } else if (p < 176) {
                *(unsigned*)(Sr + 2 * p) = 0;   // cols 334..351 zero (read by K=352)
            }
        }
    }
    __syncthreads();

    f32x4 acc[1][4];
    zero_acc(acc);
    run_layer<1, 11>(S, SA_N, wpack + WOFF_N0, w * 4, m15, q, acc);   // K=352
    __syncthreads();
    epi_act(S, SA_N, acc, nb0, w * 64, m15, q);
    __syncthreads();

    zero_acc(acc);
    run_layer<1, 8>(S, SA_N, wpack + WOFF_N1, w * 4, m15, q, acc);
    __syncthreads();
    epi_act(S, SA_N, acc, nb1, w * 64, m15, q);
    __syncthreads();

    zero_acc(acc);
    run_layer<1, 8>(S, SA_N, wpack + WOFF_N2, w * 4, m15, q, acc);

#pragma unroll
    for (int nf = 0; nf < 4; ++nf) {
        int col = w * 64 + nf * 16 + m15;
        float bv = nb2[col];
#pragma unroll
        for (int r4 = 0; r4 < 4; ++r4) {
            int jj = base + q * 4 + r4;
            if (jj < NROWS_NODE) out[(size_t)jj * 256 + col] = acc[0][nf][r4] + bv;
        }
    }
}

// ---------------- launch ----------------
extern "C" void kernel_launch(void* const* d_in, const int* in_sizes, int n_in,
                              void* d_out, int out_size, void* d_ws, size_t ws_size,
                              hipStream_t stream) {
    const float* x      = (const float*)d_in[0];
    const int*   eidx   = (const int*)d_in[1];
    const float* eattr  = (const float*)d_in[2];
    const int*   lei    = (const int*)d_in[3];
    const float* la     = (const float*)d_in[4];
    const float* h3     = (const float*)d_in[5];
    const float* eW0 = (const float*)d_in[6],  *eb0 = (const float*)d_in[7];
    const float* eW1 = (const float*)d_in[8],  *eb1 = (const float*)d_in[9];
    const float* eW2 = (const float*)d_in[10], *eb2 = (const float*)d_in[11];
    const float* nW0 = (const float*)d_in[12], *nb0 = (const float*)d_in[13];
    const float* nW1 = (const float*)d_in[14], *nb1 = (const float*)d_in[15];
    const float* nW2 = (const float*)d_in[16], *nb2 = (const float*)d_in[17];
    const float* rW0 = (const float*)d_in[18], *rb0 = (const float*)d_in[19];
    const float* rW1 = (const float*)d_in[20], *rb1 = (const float*)d_in[21];
    const float* rW2 = (const float*)d_in[22], *rb2 = (const float*)d_in[23];
    const float* rWs = (const float*)d_in[24], *rbs = (const float*)d_in[25];

    char* ws = (char*)d_ws;
    float* agg    = (float*)(ws + AGG_OFF);
    int* cnt      = (int*)(ws + CNT_OFF);
    int* cur      = (int*)(ws + CUR_OFF);
    int* ssrc     = (int*)(ws + SSRC_OFF);
    short* sdst   = (short*)(ws + SDST_OFF);
    float2* sattr = (float2*)(ws + SATTR_OFF);
    unsigned short* wpack = (unsigned short*)(ws + WPACK_OFF);

    float* out = (float*)d_out;

    hipMemsetAsync(d_ws, 0, CUR_OFF, stream);   // agg + histogram counters

    pack_weights<<<1040, 512, 0, stream>>>(eW0, eW1, eW2, nW0, nW1, nW2, rW0, rW1, rW2, wpack);
    hist_kernel<<<254, 256, 0, stream>>>(eidx + E_EDGES, cnt);
    scan_kernel<<<1, 1024, 0, stream>>>(cnt, cur);
    scatter_kernel<<<254, 256, 0, stream>>>(eidx, eidx + E_EDGES, eattr, cur,
                                            ssrc, sdst, sattr);
    edge_mlp_kernel<<<EDGE_GRID, 512, 0, stream>>>(x, h3, eb0, eb1, eb2,
                                                   wpack, ssrc, sdst, sattr, agg);
    node_tail_kernel<<<NODE_B + TAIL_B, 256, 0, stream>>>(
        h3, agg, nb0, nb1, nb2, wpack, out,
        la, rb0, rb1, rb2, rWs, rbs, lei);
}

// Round 6
// 784.894 us; speedup vs baseline: 1.3526x; 1.3526x over previous
//
#include <hip/hip_runtime.h>

// ---------------- problem constants ----------------
#define E_EDGES 64800
#define NC      842
#define NB      8          // b*t = 2*4
#define FIN     78
#define E_LAT   5894
#define NROWS_NODE (NB*NC)   // 6736
#define EPB_E    64          // edges per tile (8 waves: 2Mx4N, MF=2)
#define NT_E     1013        // ceil(64800/64), last tile has 32 valid rows
#define NODE_B   421
#define TAIL_B   192         // tail blocks fused into node dispatch

// output layout (flat float32)
#define OUT_IDX_OFF   1724416
#define OUT_IDX_N     11788
#define OUT_ATTR_OFF  1736204

// workspace layout (bytes)
#define AGG_OFF    0
#define CNT_OFF    6897664
#define CUR_OFF    6901032
#define SSRC_OFF   6904400
#define SDST_OFF   7163600
#define SATTR_OFF  7293200
#define WPACK_OFF  7811600

// packed-weight element offsets (bf16 elements)
#define WOFF_E0 0
#define WOFF_E1 40960
#define WOFF_E2 106496
#define WOFF_N0 172032
#define WOFF_N1 262144
#define WOFF_N2 327680
#define WOFF_R0 393216
#define WOFF_R1 401408
#define WOFF_R2 466944

#define WSTEP 8192   // bf16 elems per K-step stage (32 K-rows x 256 cols = 16KB)

// LDS strides (bf16 elems): dword stride ≡ 3 or 5 (mod 8) keeps b128 A-frag
// reads ≤2-way bank-aliased (free).
#define SH   262
#define SA_N 362

typedef __bf16 bf16x8 __attribute__((ext_vector_type(8)));
typedef float  f32x4  __attribute__((ext_vector_type(4)));

__device__ __forceinline__ unsigned short f2bf(float f) {   // RNE (pack_weights only)
    unsigned u = __builtin_bit_cast(unsigned, f);
    return (unsigned short)((u + 0x7fffu + ((u >> 16) & 1u)) >> 16);
}
// RTZ pack of two floats into two bf16 in one v_perm_b32
__device__ __forceinline__ unsigned packRTZ(float lo, float hi) {
    return __builtin_amdgcn_perm(__builtin_bit_cast(unsigned, hi),
                                 __builtin_bit_cast(unsigned, lo), 0x07060302u);
}

// async global->LDS DMA, 16B per lane (LDS dest = wave-uniform base + lane*16)
typedef const unsigned int __attribute__((address_space(1)))* gas1_t;
typedef unsigned int __attribute__((address_space(3)))* las3_t;
__device__ __forceinline__ void gld_lds16(const unsigned short* g, unsigned short* l) {
    __builtin_amdgcn_global_load_lds((gas1_t)(unsigned long long)g,
                                     (las3_t)(unsigned)(unsigned long long)l, 16, 0, 0);
}

template<int MF, int NF>
__device__ __forceinline__ void zero_acc(f32x4 (&acc)[MF][NF]) {
#pragma unroll
    for (int mf = 0; mf < MF; ++mf)
#pragma unroll
        for (int nf = 0; nf < NF; ++nf)
            acc[mf][nf] = (f32x4){0.f, 0.f, 0.f, 0.f};
}

// C += A_lds * Wpacked with B-fragment register prefetch (node/tail kernels).
template<int MF, int NKS>
__device__ __forceinline__ void run_layer(const unsigned short* lA, int strideA,
                                          const unsigned short* Wp, int nfg0,
                                          int m15, int q, f32x4 (&acc)[MF][4]) {
    const unsigned short* wp0 = Wp + (size_t)nfg0 * 512 + (threadIdx.x & 63) * 8;
    bf16x8 bcur[4], bnxt[4];
#pragma unroll
    for (int nf = 0; nf < 4; ++nf) bcur[nf] = *(const bf16x8*)(wp0 + nf * 512);
#pragma unroll
    for (int kk = 0; kk < NKS; ++kk) {
        if (kk + 1 < NKS) {
#pragma unroll
            for (int nf = 0; nf < 4; ++nf)
                bnxt[nf] = *(const bf16x8*)(wp0 + (size_t)(kk + 1) * 16 * 512 + nf * 512);
        }
        bf16x8 a[MF];
#pragma unroll
        for (int mf = 0; mf < MF; ++mf)
            a[mf] = *(const bf16x8*)(lA + (mf * 16 + m15) * strideA + kk * 32 + q * 8);
#pragma unroll
        for (int nf = 0; nf < 4; ++nf)
#pragma unroll
            for (int mf = 0; mf < MF; ++mf)
                acc[mf][nf] = __builtin_amdgcn_mfma_f32_16x16x32_bf16(a[mf], bcur[nf], acc[mf][nf], 0, 0, 0);
#pragma unroll
        for (int nf = 0; nf < 4; ++nf) bcur[nf] = bnxt[nf];
    }
}

// S[(rowbase+row)*stride+col] = bf16_rtz(leaky(acc + bias[col]))
template<int MF, int NF>
__device__ __forceinline__ void epi_act(unsigned short* Sb, int stride, const f32x4 (&acc)[MF][NF],
                                        const float* bias, int colbase, int rowbase,
                                        int m15, int q) {
#pragma unroll
    for (int nf = 0; nf < NF; ++nf) {
        int col = colbase + nf * 16 + m15;
        float bv = bias[col];
#pragma unroll
        for (int mf = 0; mf < MF; ++mf)
#pragma unroll
            for (int r4 = 0; r4 < 4; ++r4) {
                int row = rowbase + mf * 16 + q * 4 + r4;
                float y = acc[mf][nf][r4] + bv;
                y = fmaxf(y, 0.01f * y);
                Sb[row * stride + col] = (unsigned short)(__builtin_bit_cast(unsigned, y) >> 16);
            }
    }
}

// ---------------- weight packing ----------------
__global__ void pack_weights(const float* s0, const float* s1, const float* s2,
                             const float* s3, const float* s4, const float* s5,
                             const float* s6, const float* s7, const float* s8,
                             unsigned short* wp) {
    const int ksA[9]  = {5, 8, 8, 11, 8, 8, 1, 8, 8};
    const int kaA[9]  = {158, 256, 256, 334, 256, 256, 2, 256, 256};
    const int offA[9] = {WOFF_E0, WOFF_E1, WOFF_E2, WOFF_N0, WOFF_N1, WOFF_N2,
                         WOFF_R0, WOFF_R1, WOFF_R2};
    const float* srcs[9] = {s0, s1, s2, s3, s4, s5, s6, s7, s8};
    int rem = blockIdx.x;
    int l = 0;
    while (rem >= ksA[l] * 16) { rem -= ksA[l] * 16; ++l; }
    int kk = rem >> 4, nf = rem & 15;
    int lane = threadIdx.x >> 3, j = threadIdx.x & 7;
    int k = kk * 32 + (lane >> 4) * 8 + j;
    int n = nf * 16 + (lane & 15);
    float v = (k < kaA[l]) ? srcs[l][k * 256 + n] : 0.f;
    wp[(size_t)offA[l] + (size_t)(kk * 16 + nf) * 512 + lane * 8 + j] = f2bf(v);
}

// ---------------- counting sort of edges by dst (+ gather sorted meta) ----------------
__global__ void hist_kernel(const int* __restrict__ dstA, int* __restrict__ cnt) {
    int e = blockIdx.x * 256 + threadIdx.x;
    if (e < E_EDGES) atomicAdd(&cnt[dstA[e]], 1);
}
__global__ void scan_kernel(const int* __restrict__ cnt, int* __restrict__ cursor) {
    __shared__ int s[1024];
    int t = threadIdx.x;
    s[t] = (t < NC) ? cnt[t] : 0;
    __syncthreads();
    for (int d = 1; d < 1024; d <<= 1) {
        int v = (t >= d) ? s[t - d] : 0;
        __syncthreads();
        s[t] += v;
        __syncthreads();
    }
    if (t < NC) cursor[t] = (t == 0) ? 0 : s[t - 1];
}
__global__ void scatter_kernel(const int* __restrict__ srcA, const int* __restrict__ dstA,
                               const float* __restrict__ eattr, int* __restrict__ cursor,
                               int* __restrict__ ssrc, short* __restrict__ sdst,
                               float2* __restrict__ sattr) {
    int e = blockIdx.x * 256 + threadIdx.x;
    if (e < E_EDGES) {
        int d = dstA[e];
        int p = atomicAdd(&cursor[d], 1);
        ssrc[p] = srcA[e];
        sdst[p] = (short)d;
        sattr[p] = ((const float2*)eattr)[e];
    }
}

// ---- 2-phase pipelined layer: B staged 1 K-step ahead via global_load_lds ----
// Per phase: {issue async DMA of stage kk+1 -> ring[cur^1]; ds_read A,B from
// ring[cur]; MFMA; __syncthreads (its implicit vmcnt/lgkm drain = the dbuf
// fence)}.  The DMA has no register destination so the compiler cannot sink
// it to the use point -- its L2 latency hides under ds_read+MFMA.  The last
// phase stages the NEXT layer's stage 0 (Wnext) so layers chain seamlessly.
template<int NKS>
__device__ __forceinline__ void layer_phases(const unsigned short* Sl, unsigned short* Bb,
                                             const unsigned short* Wg,
                                             const unsigned short* Wnext,
                                             int& cur, int mh, int nw, int w, int lane,
                                             int m15, int q, f32x4 (&acc)[2][4]) {
#pragma unroll
    for (int kk = 0; kk < NKS; ++kk) {
        const unsigned short* nsrc = (kk + 1 < NKS) ? (Wg + (size_t)(kk + 1) * WSTEP) : Wnext;
        if (nsrc) {
#pragma unroll
            for (int r = 0; r < 2; ++r)
                gld_lds16(nsrc + r * 4096 + w * 512 + lane * 8,
                          Bb + (cur ^ 1) * WSTEP + r * 4096 + w * 512);
        }
        bf16x8 a[2], bfr[4];
#pragma unroll
        for (int mf = 0; mf < 2; ++mf)
            a[mf] = *(const bf16x8*)(Sl + (mh * 32 + mf * 16 + m15) * SH + kk * 32 + q * 8);
#pragma unroll
        for (int nf = 0; nf < 4; ++nf)
            bfr[nf] = *(const bf16x8*)(Bb + cur * WSTEP + (nw * 4 + nf) * 512 + lane * 8);
#pragma unroll
        for (int nf = 0; nf < 4; ++nf)
#pragma unroll
            for (int mf = 0; mf < 2; ++mf)
                acc[mf][nf] = __builtin_amdgcn_mfma_f32_16x16x32_bf16(a[mf], bfr[nf], acc[mf][nf], 0, 0, 0);
        __syncthreads();
        cur ^= 1;
    }
}

// ------- fused edge MLP: 64-edge tiles, 512 thr (2M x 4N waves), LDS B-ring --
__global__ __launch_bounds__(512, 4) void edge_mlp_kernel(
    const float* __restrict__ x, const float* __restrict__ h3,
    const float* __restrict__ eb0, const float* __restrict__ eb1, const float* __restrict__ eb2,
    const unsigned short* __restrict__ wpack, const int* __restrict__ ssrc,
    const short* __restrict__ sdst, const float2* __restrict__ sattr,
    float* __restrict__ agg) {
    __shared__ __align__(16) unsigned short S[64 * SH];      // A(160) then H(256) overlay
    __shared__ __align__(16) unsigned short Bb[2 * WSTEP];   // weight ring, 2 x 16KB
    __shared__ short dstl[EPB_E];
    __shared__ unsigned char starts[EPB_E + 4];
    __shared__ int nseg;

    const int tid = threadIdx.x, lane = tid & 63, w = tid >> 6;
    const int m15 = lane & 15, q = lane >> 4;
    const int nw = w & 3, mh = w >> 2;
    const int base = blockIdx.x * EPB_E, b = blockIdx.y;
    const int ne = min(EPB_E, E_EDGES - base);

    if (tid < EPB_E) dstl[tid] = (tid < ne) ? sdst[base + tid] : (short)-1;
    __syncthreads();

    // issue stage 0 of L0 now -- overlaps the x/h3 gather below
    {
        const unsigned short* s0 = wpack + WOFF_E0;
#pragma unroll
        for (int r = 0; r < 2; ++r)
            gld_lds16(s0 + r * 4096 + w * 512 + lane * 8, Bb + r * 4096 + w * 512);
    }

    if (tid == 0) {   // serial segment scan over valid rows
        int ns = 0; short prev = -2;
        for (int r = 0; r < ne; ++r) {
            short d = dstl[r];
            if (d != prev) { starts[ns++] = (unsigned char)r; prev = d; }
        }
        starts[ns] = (unsigned char)ne;
        nseg = ns;
    }

    // stage layer-0 input [x(78)|h3(78)|attr(2)|pad(2)] at stride SH, RTZ pack.
    // 8 threads per row, 64 rows in one pass (512 threads); invalid rows zeroed.
    {
        const int rr = tid >> 3, j = tid & 7;
        unsigned short* Sr = S + rr * SH;
        if (rr < ne) {
            const int eg = base + rr;
            const float* xr = x + ((size_t)b * E_EDGES + ssrc[eg]) * FIN;
            const float* hr = h3 + (int)dstl[rr] * FIN;
#pragma unroll
            for (int t = 0; t < 5; ++t) {
                int p = j + 8 * t;
                if (p < 39) {
                    float2 f = *(const float2*)(xr + 2 * p);
                    float2 g = *(const float2*)(hr + 2 * p);
                    *(unsigned*)(Sr + 2 * p) = packRTZ(f.x, f.y);
                    *(unsigned*)(Sr + 78 + 2 * p) = packRTZ(g.x, g.y);
                } else if (p == 39) {
                    float2 a2 = sattr[eg];
                    *(unsigned*)(Sr + 156) = packRTZ(a2.x, a2.y);
                    *(unsigned*)(Sr + 158) = 0;
                }
            }
        } else {
#pragma unroll
            for (int t = 0; t < 5; ++t) {
                int p = j + 8 * t;
                if (p < 39) {
                    *(unsigned*)(Sr + 2 * p) = 0;
                    *(unsigned*)(Sr + 78 + 2 * p) = 0;
                } else if (p == 39) {
                    *(unsigned*)(Sr + 156) = 0;
                    *(unsigned*)(Sr + 158) = 0;
                }
            }
        }
    }
    float bnf[4];
#pragma unroll
    for (int nf = 0; nf < 4; ++nf) bnf[nf] = eb2[nw * 64 + nf * 16 + m15];
    __syncthreads();   // drains gather + stage0 DMA (implicit vmcnt(0))

    int cur = 0;
    f32x4 acc[2][4];
    zero_acc(acc);
    layer_phases<5>(S, Bb, wpack + WOFF_E0, wpack + WOFF_E1, cur, mh, nw, w, lane, m15, q, acc);
    epi_act(S, SH, acc, eb0, nw * 64, mh * 32, m15, q);
    __syncthreads();

    zero_acc(acc);
    layer_phases<8>(S, Bb, wpack + WOFF_E1, wpack + WOFF_E2, cur, mh, nw, w, lane, m15, q, acc);
    epi_act(S, SH, acc, eb1, nw * 64, mh * 32, m15, q);
    __syncthreads();

    zero_acc(acc);
    layer_phases<8>(S, Bb, wpack + WOFF_E2, (const unsigned short*)0, cur, mh, nw, w, lane, m15, q, acc);

    // segment reduce + predicated atomic flush; each M-half wave covers its
    // own 32-row window, adding bias * (rows of segment in window).
    const int ns = nseg;
#pragma unroll
    for (int nf = 0; nf < 4; ++nf) {
        for (int s = 0; s < ns; ++s) {
            const int lo = starts[s], hi = starts[s + 1];
            float tv = 0.f;
#pragma unroll
            for (int mf = 0; mf < 2; ++mf)
#pragma unroll
                for (int r4 = 0; r4 < 4; ++r4) {
                    int row = mh * 32 + mf * 16 + q * 4 + r4;
                    tv += (row >= lo && row < hi) ? acc[mf][nf][r4] : 0.f;
                }
            tv += __shfl_xor(tv, 16, 64);
            tv += __shfl_xor(tv, 32, 64);
            if (q == nf) {
                int cnt = min(hi, mh * 32 + 32) - max(lo, mh * 32);
                if (cnt > 0) {
                    int dc = dstl[lo];
                    atomicAdd(&agg[((size_t)b * NC + dc) * 256 + nw * 64 + nf * 16 + m15],
                              tv + bnf[nf] * (float)cnt);
                }
            }
        }
    }
}

// ------- node MLP (16-row tiles, MF=1, overlay) + fused tail blocks ----------
__global__ __launch_bounds__(256, 4) void node_tail_kernel(
    const float* __restrict__ h3, const float* __restrict__ agg,
    const float* __restrict__ nb0, const float* __restrict__ nb1, const float* __restrict__ nb2,
    const unsigned short* __restrict__ wpack, float* __restrict__ out,
    const float* __restrict__ la, const float* __restrict__ rb0,
    const float* __restrict__ rb1, const float* __restrict__ rb2,
    const float* __restrict__ rWs, const float* __restrict__ rbs,
    const int* __restrict__ lei) {
    __shared__ __align__(16) unsigned short S[32 * SH];   // covers 16*SA_N too

    const int tid = threadIdx.x, lane = tid & 63, w = tid >> 6;
    const int m15 = lane & 15, q = lane >> 4;

    if (blockIdx.x >= NODE_B) {   // ---------------- tail path ----------------
        const int blk = blockIdx.x - NODE_B;
        if (blk >= 185) {   // idx passthrough: float(latent_edge_index)
            for (int i = (blk - 185) * 256 + tid; i < OUT_IDX_N; i += 7 * 256)
                out[OUT_IDX_OFF + i] = (float)lei[i];
            return;
        }
        const int base = blk * 32;
        {   // stage [la(2)|zero(30)] at stride SH; 8 lanes per row, 16 pairs
            const int rr = tid >> 3, jj = tid & 7;
            unsigned short* Sr = S + rr * SH;
            unsigned v0 = 0;
            if (jj == 0 && base + rr < E_LAT) {
                float2 f = *(const float2*)(la + (size_t)(base + rr) * 2);
                v0 = packRTZ(f.x, f.y);
            }
            *(unsigned*)(Sr + 2 * jj) = v0;
            *(unsigned*)(Sr + 2 * (jj + 8)) = 0;
        }
        __syncthreads();

        f32x4 acc[2][4];
        zero_acc(acc);
        run_layer<2, 1>(S, SH, wpack + WOFF_R0, w * 4, m15, q, acc);   // K=32 (2 real)
        __syncthreads();
        epi_act(S, SH, acc, rb0, w * 64, 0, m15, q);
        __syncthreads();

        zero_acc(acc);
        run_layer<2, 8>(S, SH, wpack + WOFF_R1, w * 4, m15, q, acc);
        __syncthreads();
        epi_act(S, SH, acc, rb1, w * 64, 0, m15, q);
        __syncthreads();

        zero_acc(acc);
        run_layer<2, 8>(S, SH, wpack + WOFF_R2, w * 4, m15, q, acc);

        float* outA = out + OUT_ATTR_OFF;
#pragma unroll
        for (int nf = 0; nf < 4; ++nf) {
            int col = w * 64 + nf * 16 + m15;
            float bv = rb2[col] + rbs[col];
            float ws0 = rWs[col], ws1 = rWs[256 + col];
#pragma unroll
            for (int mf = 0; mf < 2; ++mf)
#pragma unroll
                for (int r4 = 0; r4 < 4; ++r4) {
                    int row = mf * 16 + q * 4 + r4;
                    int e = base + row;
                    if (e < E_LAT) {
                        float v = acc[mf][nf][r4] + bv + la[e * 2] * ws0 + la[e * 2 + 1] * ws1;
                        outA[(size_t)e * 256 + col] = v;
                    }
                }
        }
        return;
    }

    // ---------------- node path ----------------
    const int base = blockIdx.x * 16;

    // stage [h3(78)|agg(256)|zero(18)] at stride SA_N; 16 lanes per row
    {
        const int rr = tid >> 4, l16 = tid & 15;
        const int jj = base + rr;
        const int vl = jj < NROWS_NODE;
        const int c = vl ? jj % NC : 0;
        const float* hr = h3 + c * FIN;
        const float* ar = agg + (size_t)jj * 256;
        unsigned short* Sr = S + rr * SA_N;
#pragma unroll
        for (int tt = 0; tt < 12; ++tt) {
            int p = l16 + 16 * tt;
            if (p < 39) {
                float2 f = *(const float2*)(hr + 2 * p);
                *(unsigned*)(Sr + 2 * p) = packRTZ(f.x, f.y);
            } else if (p < 167) {
                unsigned v = 0;
                if (vl) { float2 f = *(const float2*)(ar + 2 * p - 78); v = packRTZ(f.x, f.y); }
                *(unsigned*)(Sr + 2 * p) = v;
            } else if (p < 176) {
                *(unsigned*)(Sr + 2 * p) = 0;   // cols 334..351 zero (read by K=352)
            }
        }
    }
    __syncthreads();

    f32x4 acc[1][4];
    zero_acc(acc);
    run_layer<1, 11>(S, SA_N, wpack + WOFF_N0, w * 4, m15, q, acc);   // K=352
    __syncthreads();
    epi_act(S, SA_N, acc, nb0, w * 64, 0, m15, q);
    __syncthreads();

    zero_acc(acc);
    run_layer<1, 8>(S, SA_N, wpack + WOFF_N1, w * 4, m15, q, acc);
    __syncthreads();
    epi_act(S, SA_N, acc, nb1, w * 64, 0, m15, q);
    __syncthreads();

    zero_acc(acc);
    run_layer<1, 8>(S, SA_N, wpack + WOFF_N2, w * 4, m15, q, acc);

#pragma unroll
    for (int nf = 0; nf < 4; ++nf) {
        int col = w * 64 + nf * 16 + m15;
        float bv = nb2[col];
#pragma unroll
        for (int r4 = 0; r4 < 4; ++r4) {
            int jj = base + q * 4 + r4;
            if (jj < NROWS_NODE) out[(size_t)jj * 256 + col] = acc[0][nf][r4] + bv;
        }
    }
}

// ---------------- launch ----------------
extern "C" void kernel_launch(void* const* d_in, const int* in_sizes, int n_in,
                              void* d_out, int out_size, void* d_ws, size_t ws_size,
                              hipStream_t stream) {
    const float* x      = (const float*)d_in[0];
    const int*   eidx   = (const int*)d_in[1];
    const float* eattr  = (const float*)d_in[2];
    const int*   lei    = (const int*)d_in[3];
    const float* la     = (const float*)d_in[4];
    const float* h3     = (const float*)d_in[5];
    const float* eW0 = (const float*)d_in[6],  *eb0 = (const float*)d_in[7];
    const float* eW1 = (const float*)d_in[8],  *eb1 = (const float*)d_in[9];
    const float* eW2 = (const float*)d_in[10], *eb2 = (const float*)d_in[11];
    const float* nW0 = (const float*)d_in[12], *nb0 = (const float*)d_in[13];
    const float* nW1 = (const float*)d_in[14], *nb1 = (const float*)d_in[15];
    const float* nW2 = (const float*)d_in[16], *nb2 = (const float*)d_in[17];
    const float* rW0 = (const float*)d_in[18], *rb0 = (const float*)d_in[19];
    const float* rW1 = (const float*)d_in[20], *rb1 = (const float*)d_in[21];
    const float* rW2 = (const float*)d_in[22], *rb2 = (const float*)d_in[23];
    const float* rWs = (const float*)d_in[24], *rbs = (const float*)d_in[25];

    char* ws = (char*)d_ws;
    float* agg    = (float*)(ws + AGG_OFF);
    int* cnt      = (int*)(ws + CNT_OFF);
    int* cur      = (int*)(ws + CUR_OFF);
    int* ssrc     = (int*)(ws + SSRC_OFF);
    short* sdst   = (short*)(ws + SDST_OFF);
    float2* sattr = (float2*)(ws + SATTR_OFF);
    unsigned short* wpack = (unsigned short*)(ws + WPACK_OFF);

    float* out = (float*)d_out;

    hipMemsetAsync(d_ws, 0, CUR_OFF, stream);   // agg + histogram counters

    pack_weights<<<1040, 512, 0, stream>>>(eW0, eW1, eW2, nW0, nW1, nW2, rW0, rW1, rW2, wpack);
    hist_kernel<<<254, 256, 0, stream>>>(eidx + E_EDGES, cnt);
    scan_kernel<<<1, 1024, 0, stream>>>(cnt, cur);
    scatter_kernel<<<254, 256, 0, stream>>>(eidx, eidx + E_EDGES, eattr, cur,
                                            ssrc, sdst, sattr);
    edge_mlp_kernel<<<dim3(NT_E, NB), 512, 0, stream>>>(x, h3, eb0, eb1, eb2,
                                                        wpack, ssrc, sdst, sattr, agg);
    node_tail_kernel<<<NODE_B + TAIL_B, 256, 0, stream>>>(
        h3, agg, nb0, nb1, nb2, wpack, out,
        la, rb0, rb1, rb2, rWs, rbs, lei);
}